// Round 3
// baseline (131.021 us; speedup 1.0000x reference)
//
#include <hip/hip_runtime.h>

// GraphSearchPolicy, two-kernel design for MI355X (gfx950).
// B=2048, A=256, DE=128, DH=256, DR=128, DIN=512, ACT=256.
//
// Kernel A: h = relu(concat(E,H,Q) @ W1 + b1) -> ws    [B x ACT]
//   grid 1024 = (B/8 rowgroups) x (4 colgroups of 64), 256 threads.
//   Col-split adds blocks at zero extra W1 L2 traffic -> 16 waves/CU.
// Kernel B: x2 = h @ W2 + b2; logits = gather(rel_emb) . x2; softmax+entropy
//   grid 512 = B/4, 512 threads -> 16 waves/CU.

#define DE   128
#define DH   256
#define DR   128
#define DIN  512
#define ACT  256
#define AA   256

// ---------------------------------------------------------------- kernel A
__global__ __launch_bounds__(256, 4) void mlp1_kernel(
    const int*   __restrict__ e,
    const int*   __restrict__ q,
    const float* __restrict__ H,
    const float* __restrict__ entity_emb,
    const float* __restrict__ rel_emb,
    const float* __restrict__ W1,
    const float* __restrict__ b1,
    float*       __restrict__ hout)
{
    __shared__ float xs[8][520];            // 8 rows x 512, pad 520 (520%32=8)
    const int t  = threadIdx.x;
    const int cg = blockIdx.x & 3;          // 64-col group
    const int rg = blockIdx.x >> 2;         // 8-row group
    const int b0 = rg * 8;

    // ---- stage X rows (concat E,H,Q), coalesced float4 ----
    {
        const int row = t >> 5;             // 0..7
        const int seg = t & 31;             // 16 floats each
        const int b   = b0 + row;
        const int eb  = e[b];
        const int qb  = q[b];
        #pragma unroll
        for (int j = 0; j < 4; ++j) {
            const int c = seg * 16 + j * 4;
            float4 v;
            if (c < DE)           v = *(const float4*)&entity_emb[(size_t)eb * DE + c];
            else if (c < DE + DH) v = *(const float4*)&H[(size_t)b * DH + (c - DE)];
            else                  v = *(const float4*)&rel_emb[(size_t)qb * DR + (c - DE - DH)];
            *(float4*)&xs[row][c] = v;
        }
    }
    __syncthreads();

    // ---- layer 1: thread = (row, colpair) ----
    const int row = t >> 5;                 // 0..7
    const int cp  = t & 31;                 // 0..31
    const int col = cg * 64 + cp * 2;
    const float2 bv = *(const float2*)&b1[col];
    float c0 = bv.x, c1 = bv.y;
    const float* xrow = xs[row];
    #pragma unroll 16
    for (int k = 0; k < DIN; ++k) {
        const float2 w  = *(const float2*)&W1[(size_t)k * ACT + col];  // 256B/wave, L1/L2-hot
        const float  xv = xrow[k];                                     // LDS broadcast
        c0 = fmaf(xv, w.x, c0);
        c1 = fmaf(xv, w.y, c1);
    }
    float2 hv;
    hv.x = fmaxf(c0, 0.f);
    hv.y = fmaxf(c1, 0.f);
    *(float2*)&hout[(size_t)(b0 + row) * ACT + col] = hv;
}

// ---------------------------------------------------------------- kernel B
__global__ __launch_bounds__(512, 4) void mlp2_kernel(
    const float* __restrict__ hin,
    const int*   __restrict__ r_space,
    const float* __restrict__ r_mask,
    const float* __restrict__ rel_emb,
    const float* __restrict__ W2,
    const float* __restrict__ b2,
    float*       __restrict__ dist_out,
    float*       __restrict__ ent_out)
{
    __shared__ float hs[4][ACT];            // 4 KB
    __shared__ float x2s[4][DR];            // 2 KB
    __shared__ float wredM[8][2], wredS[8][2], wredL[8][2];

    const int t  = threadIdx.x;             // 0..511
    const int b0 = blockIdx.x * 4;

    // ---- early loads: action indices + masks (hide latency under layer 2) ----
    const int a  = t & 255;                 // action
    const int rp = t >> 8;                  // rowpair 0..1 -> rows {2rp, 2rp+1}
    const int r0 = 2 * rp, r1 = 2 * rp + 1;
    const int   ridx0 = r_space[(size_t)(b0 + r0) * AA + a];
    const int   ridx1 = r_space[(size_t)(b0 + r1) * AA + a];
    const float msk0  = r_mask [(size_t)(b0 + r0) * AA + a];
    const float msk1  = r_mask [(size_t)(b0 + r1) * AA + a];

    // ---- stage h (4 rows x 256), coalesced float2 ----
    {
        const int i   = t * 2;              // 0..1022
        const int row = i >> 8;             // 0..3
        const int c   = i & 255;
        *(float2*)&hs[row][c] = *(const float2*)&hin[(size_t)(b0 + row) * ACT + c];
    }
    __syncthreads();

    // ---- layer 2: thread = (row, col); 512 = 4 rows x 128 cols ----
    {
        const int l2row = t >> 7;           // 0..3 (wave-uniform)
        const int l2col = t & 127;
        float acc = b2[l2col];
        const float* hr = hs[l2row];
        #pragma unroll 16
        for (int k = 0; k < ACT; ++k)
            acc = fmaf(hr[k], W2[(size_t)k * DR + l2col], acc);   // LDS bcast + 256B/wave
        x2s[l2row][l2col] = acc;
    }
    __syncthreads();

    // ---- logits: thread = (action a, rows r0,r1); 16 b128 gathers in flight ----
    float lg0, lg1;
    {
        const float4* rr0 = (const float4*)&rel_emb[(size_t)ridx0 * DR];
        const float4* rr1 = (const float4*)&rel_emb[(size_t)ridx1 * DR];
        const float4* xx0 = (const float4*)&x2s[r0][0];
        const float4* xx1 = (const float4*)&x2s[r1][0];
        float s0 = 0.f, s1 = 0.f;
        #pragma unroll
        for (int d = 0; d < DR / 4; ++d) {
            const float4 u0 = rr0[d];
            const float4 u1 = rr1[d];
            const float4 v0 = xx0[d];       // broadcast
            const float4 v1 = xx1[d];
            s0 = fmaf(u0.x, v0.x, s0); s0 = fmaf(u0.y, v0.y, s0);
            s0 = fmaf(u0.z, v0.z, s0); s0 = fmaf(u0.w, v0.w, s0);
            s1 = fmaf(u1.x, v1.x, s1); s1 = fmaf(u1.y, v1.y, s1);
            s1 = fmaf(u1.z, v1.z, s1); s1 = fmaf(u1.w, v1.w, s1);
        }
        lg0 = s0 - (1.0f - msk0) * 1e31f;
        lg1 = s1 - (1.0f - msk1) * 1e31f;
    }

    const int wv = t >> 6;                  // wave 0..7; waves [rp*4, rp*4+4) share rows

    // ---- max ----
    float m0 = lg0, m1 = lg1;
    #pragma unroll
    for (int off = 32; off >= 1; off >>= 1) {
        m0 = fmaxf(m0, __shfl_xor(m0, off, 64));
        m1 = fmaxf(m1, __shfl_xor(m1, off, 64));
    }
    if ((t & 63) == 0) { wredM[wv][0] = m0; wredM[wv][1] = m1; }
    __syncthreads();
    {
        const int wb = rp * 4;
        m0 = fmaxf(fmaxf(wredM[wb][0], wredM[wb+1][0]), fmaxf(wredM[wb+2][0], wredM[wb+3][0]));
        m1 = fmaxf(fmaxf(wredM[wb][1], wredM[wb+1][1]), fmaxf(wredM[wb+2][1], wredM[wb+3][1]));
    }

    // ---- exp + joint sum of S and SL = sum p*(lg-m) ----
    const float z0 = lg0 - m0, z1 = lg1 - m1;
    const float p0 = __expf(z0), p1 = __expf(z1);
    float s0 = p0, s1 = p1, sl0 = p0 * z0, sl1 = p1 * z1;
    #pragma unroll
    for (int off = 32; off >= 1; off >>= 1) {
        s0  += __shfl_xor(s0,  off, 64);
        s1  += __shfl_xor(s1,  off, 64);
        sl0 += __shfl_xor(sl0, off, 64);
        sl1 += __shfl_xor(sl1, off, 64);
    }
    if ((t & 63) == 0) {
        wredS[wv][0] = s0;  wredS[wv][1] = s1;
        wredL[wv][0] = sl0; wredL[wv][1] = sl1;
    }
    __syncthreads();
    float S0, S1, SL0, SL1;
    {
        const int wb = rp * 4;
        S0  = wredS[wb][0] + wredS[wb+1][0] + wredS[wb+2][0] + wredS[wb+3][0];
        S1  = wredS[wb][1] + wredS[wb+1][1] + wredS[wb+2][1] + wredS[wb+3][1];
        SL0 = wredL[wb][0] + wredL[wb+1][0] + wredL[wb+2][0] + wredL[wb+3][0];
        SL1 = wredL[wb][1] + wredL[wb+1][1] + wredL[wb+2][1] + wredL[wb+3][1];
    }

    // ---- outputs ----
    dist_out[(size_t)(b0 + r0) * AA + a] = p0 / S0;
    dist_out[(size_t)(b0 + r1) * AA + a] = p1 / S1;
    if (t == 0) {                           // wave 0 holds rows 0,1
        ent_out[b0 + 0] = __logf(S0) - SL0 / S0;
        ent_out[b0 + 1] = __logf(S1) - SL1 / S1;
    }
    if (t == 256) {                         // wave 4 holds rows 2,3
        ent_out[b0 + 2] = __logf(S0) - SL0 / S0;
        ent_out[b0 + 3] = __logf(S1) - SL1 / S1;
    }
}

// ---------------------------------------------------------------- launcher
extern "C" void kernel_launch(void* const* d_in, const int* in_sizes, int n_in,
                              void* d_out, int out_size, void* d_ws, size_t ws_size,
                              hipStream_t stream) {
    const int*   e          = (const int*)  d_in[0];
    const int*   q          = (const int*)  d_in[1];
    const float* H          = (const float*)d_in[2];
    const int*   r_space    = (const int*)  d_in[3];
    const float* r_mask     = (const float*)d_in[4];
    const float* entity_emb = (const float*)d_in[5];
    const float* rel_emb    = (const float*)d_in[6];
    const float* W1         = (const float*)d_in[7];
    const float* b1         = (const float*)d_in[8];
    const float* W2         = (const float*)d_in[9];
    const float* b2         = (const float*)d_in[10];

    const int B = in_sizes[0];              // 2048
    float* dist_out = (float*)d_out;                    // [B, 256]
    float* ent_out  = (float*)d_out + (size_t)B * AA;   // [B]
    float* h_ws     = (float*)d_ws;                     // [B, 256] = 2 MB

    mlp1_kernel<<<(B / 8) * 4, 256, 0, stream>>>(
        e, q, H, entity_emb, rel_emb, W1, b1, h_ws);
    mlp2_kernel<<<B / 4, 512, 0, stream>>>(
        h_ws, r_space, r_mask, rel_emb, W2, b2, dist_out, ent_out);
}

// Round 4
// 49.715 us; speedup vs baseline: 2.6354x; 2.6354x over previous
//
#include <hip/hip_runtime.h>

// GraphSearchPolicy fused single-kernel, split-K MLP, for MI355X (gfx950).
// B=2048, A=256, DE=128, DH=256, DR=128, DIN=512, ACT=256, NR=1000.
// Grid 512 blocks x 512 threads (8 waves) -> 2 blocks/CU, 16 waves/CU.
// Layer1: wave ks owns k in [ks*64,+64), thread owns col-quad -> float4 W1 loads.
// Layer2: wave ks owns k in [ks*32,+32), thread owns col-pair -> float2 W2 loads.
// Partials combined via LDS (per-instruction conflict-free layouts).

#define DE   128
#define DH   256
#define DR   128
#define DIN  512
#define ACT  256
#define AA   256
#define BB   4

__global__ __launch_bounds__(512, 4) void policy_kernel(
    const int*   __restrict__ e,
    const int*   __restrict__ q,
    const float* __restrict__ H,
    const int*   __restrict__ r_space,
    const float* __restrict__ r_mask,
    const float* __restrict__ entity_emb,
    const float* __restrict__ rel_emb,
    const float* __restrict__ W1,
    const float* __restrict__ b1,
    const float* __restrict__ W2,
    const float* __restrict__ b2,
    float* __restrict__ dist_out,
    float* __restrict__ ent_out)
{
    const int t  = threadIdx.x;            // 0..511
    const int b0 = blockIdx.x * BB;

    __shared__ __align__(16) float xvT[DIN * BB];        // [k][row]  8 KB
    __shared__ __align__(16) float part[8 * BB * ACT];   // [ks][row][col] 32 KB (reused)
    __shared__ __align__(16) float hvT[ACT * BB];        // [k][row]  4 KB
    __shared__ __align__(16) float x2s[BB][DR];          // 2 KB
    __shared__ float wredM[8][2], wredS[8][2], wredL[8][2];

    // ---- early loads: action indices + masks (HBM latency hides under MLP) ----
    const int a  = t & 255;
    const int rp = t >> 8;                 // 0..1 -> rows {2rp, 2rp+1}
    const int rA = 2 * rp, rB = rA + 1;
    const int   ridx0 = r_space[(size_t)(b0 + rA) * AA + a];
    const int   ridx1 = r_space[(size_t)(b0 + rB) * AA + a];
    const float msk0  = r_mask [(size_t)(b0 + rA) * AA + a];
    const float msk1  = r_mask [(size_t)(b0 + rB) * AA + a];

    // ---- stage X = concat(E,H,Q) transposed into xvT[k][row] ----
    {
        const int row = t >> 7;            // 0..3
        const int c   = (t & 127) * 4;     // 0..508
        const int b   = b0 + row;
        float4 v;
        if (c < DE)            v = *(const float4*)&entity_emb[(size_t)e[b] * DE + c];
        else if (c < DE + DH)  v = *(const float4*)&H[(size_t)b * DH + (c - DE)];
        else                   v = *(const float4*)&rel_emb[(size_t)q[b] * DR + (c - DE - DH)];
        xvT[(c + 0) * BB + row] = v.x;     // one-time scatter; conflicts negligible
        xvT[(c + 1) * BB + row] = v.y;
        xvT[(c + 2) * BB + row] = v.z;
        xvT[(c + 3) * BB + row] = v.w;
    }
    __syncthreads();

    // ---- layer 1 partials: wave ks, thread col-quad cq ----
    {
        const int cq = t & 63;
        const int ks = t >> 6;             // wave id 0..7
        float4 a0 = {0,0,0,0}, a1 = {0,0,0,0}, a2 = {0,0,0,0}, a3 = {0,0,0,0};
        const float* wbase = &W1[(size_t)(ks * 64) * ACT + cq * 4];
        const float* xbase = &xvT[(ks * 64) * BB];
        #pragma unroll 8
        for (int kk = 0; kk < 64; ++kk) {
            const float4 w = *(const float4*)(wbase + (size_t)kk * ACT);  // 1KB/wave
            const float4 x = *(const float4*)(xbase + kk * BB);           // b128 bcast
            a0.x = fmaf(w.x, x.x, a0.x); a0.y = fmaf(w.y, x.x, a0.y);
            a0.z = fmaf(w.z, x.x, a0.z); a0.w = fmaf(w.w, x.x, a0.w);
            a1.x = fmaf(w.x, x.y, a1.x); a1.y = fmaf(w.y, x.y, a1.y);
            a1.z = fmaf(w.z, x.y, a1.z); a1.w = fmaf(w.w, x.y, a1.w);
            a2.x = fmaf(w.x, x.z, a2.x); a2.y = fmaf(w.y, x.z, a2.y);
            a2.z = fmaf(w.z, x.z, a2.z); a2.w = fmaf(w.w, x.z, a2.w);
            a3.x = fmaf(w.x, x.w, a3.x); a3.y = fmaf(w.y, x.w, a3.y);
            a3.z = fmaf(w.z, x.w, a3.z); a3.w = fmaf(w.w, x.w, a3.w);
        }
        float* pb = &part[(size_t)(ks * BB) * ACT + cq * 4];
        *(float4*)(pb + 0 * ACT) = a0;     // contiguous cols per wave: conflict-free
        *(float4*)(pb + 1 * ACT) = a1;
        *(float4*)(pb + 2 * ACT) = a2;
        *(float4*)(pb + 3 * ACT) = a3;
    }
    __syncthreads();

    // ---- combine + bias + ReLU -> hvT[k][row] ----
    #pragma unroll
    for (int o = t; o < BB * ACT; o += 512) {
        const int row = o >> 8;            // 0..3
        const int col = o & 255;
        float s = b1[col];
        #pragma unroll
        for (int ks = 0; ks < 8; ++ks)
            s += part[(ks * BB + row) * ACT + col];   // lanes: consecutive cols
        hvT[col * BB + row] = fmaxf(s, 0.f);
    }
    __syncthreads();

    // ---- layer 2 partials: wave ks2, thread col-pair cp ----
    {
        const int cp  = t & 63;
        const int ks2 = t >> 6;            // 0..7
        float2 c0 = {0,0}, c1 = {0,0}, c2 = {0,0}, c3 = {0,0};
        const float* wbase = &W2[(size_t)(ks2 * 32) * DR + cp * 2];
        const float* hbase = &hvT[(ks2 * 32) * BB];
        #pragma unroll 8
        for (int kk = 0; kk < 32; ++kk) {
            const float2 w  = *(const float2*)(wbase + (size_t)kk * DR);  // 512B/wave
            const float4 h4 = *(const float4*)(hbase + kk * BB);          // b128 bcast
            c0.x = fmaf(w.x, h4.x, c0.x); c0.y = fmaf(w.y, h4.x, c0.y);
            c1.x = fmaf(w.x, h4.y, c1.x); c1.y = fmaf(w.y, h4.y, c1.y);
            c2.x = fmaf(w.x, h4.z, c2.x); c2.y = fmaf(w.y, h4.z, c2.y);
            c3.x = fmaf(w.x, h4.w, c3.x); c3.y = fmaf(w.y, h4.w, c3.y);
        }
        float* pb = &part[(size_t)(ks2 * BB) * DR + cp * 2];
        *(float2*)(pb + 0 * DR) = c0;
        *(float2*)(pb + 1 * DR) = c1;
        *(float2*)(pb + 2 * DR) = c2;
        *(float2*)(pb + 3 * DR) = c3;
    }
    __syncthreads();

    // ---- combine2 + bias -> x2s[row][col] ----
    {
        const int row = t >> 7;            // 0..3
        const int col = t & 127;
        float s = b2[col];
        #pragma unroll
        for (int ks = 0; ks < 8; ++ks)
            s += part[(ks * BB + row) * DR + col];
        x2s[row][col] = s;
    }
    __syncthreads();

    // ---- logits: thread = (action a, rows rA,rB) ----
    float lg0, lg1;
    {
        const float4* rr0 = (const float4*)&rel_emb[(size_t)ridx0 * DR];
        const float4* rr1 = (const float4*)&rel_emb[(size_t)ridx1 * DR];
        const float4* xx0 = (const float4*)&x2s[rA][0];
        const float4* xx1 = (const float4*)&x2s[rB][0];
        float s0 = 0.f, s1 = 0.f;
        #pragma unroll 4
        for (int d = 0; d < DR / 4; ++d) {
            const float4 u0 = rr0[d];
            const float4 u1 = rr1[d];
            const float4 v0 = xx0[d];      // broadcast
            const float4 v1 = xx1[d];
            s0 = fmaf(u0.x, v0.x, s0); s0 = fmaf(u0.y, v0.y, s0);
            s0 = fmaf(u0.z, v0.z, s0); s0 = fmaf(u0.w, v0.w, s0);
            s1 = fmaf(u1.x, v1.x, s1); s1 = fmaf(u1.y, v1.y, s1);
            s1 = fmaf(u1.z, v1.z, s1); s1 = fmaf(u1.w, v1.w, s1);
        }
        lg0 = s0 - (1.0f - msk0) * 1e31f;
        lg1 = s1 - (1.0f - msk1) * 1e31f;
    }

    const int wv = t >> 6;                 // waves 0..3 -> rp 0 (rows 0,1); 4..7 -> rp 1

    // ---- max ----
    float m0 = lg0, m1 = lg1;
    #pragma unroll
    for (int off = 32; off >= 1; off >>= 1) {
        m0 = fmaxf(m0, __shfl_xor(m0, off, 64));
        m1 = fmaxf(m1, __shfl_xor(m1, off, 64));
    }
    if ((t & 63) == 0) { wredM[wv][0] = m0; wredM[wv][1] = m1; }
    __syncthreads();
    {
        const int wb = rp * 4;
        m0 = fmaxf(fmaxf(wredM[wb][0], wredM[wb+1][0]), fmaxf(wredM[wb+2][0], wredM[wb+3][0]));
        m1 = fmaxf(fmaxf(wredM[wb][1], wredM[wb+1][1]), fmaxf(wredM[wb+2][1], wredM[wb+3][1]));
    }

    // ---- exp + joint sums S, SL = sum p*(lg-m) ----
    const float z0 = lg0 - m0, z1 = lg1 - m1;
    const float p0 = __expf(z0), p1 = __expf(z1);
    float s0 = p0, s1 = p1, sl0 = p0 * z0, sl1 = p1 * z1;
    #pragma unroll
    for (int off = 32; off >= 1; off >>= 1) {
        s0  += __shfl_xor(s0,  off, 64);
        s1  += __shfl_xor(s1,  off, 64);
        sl0 += __shfl_xor(sl0, off, 64);
        sl1 += __shfl_xor(sl1, off, 64);
    }
    if ((t & 63) == 0) {
        wredS[wv][0] = s0;  wredS[wv][1] = s1;
        wredL[wv][0] = sl0; wredL[wv][1] = sl1;
    }
    __syncthreads();
    float S0, S1, SL0, SL1;
    {
        const int wb = rp * 4;
        S0  = wredS[wb][0] + wredS[wb+1][0] + wredS[wb+2][0] + wredS[wb+3][0];
        S1  = wredS[wb][1] + wredS[wb+1][1] + wredS[wb+2][1] + wredS[wb+3][1];
        SL0 = wredL[wb][0] + wredL[wb+1][0] + wredL[wb+2][0] + wredL[wb+3][0];
        SL1 = wredL[wb][1] + wredL[wb+1][1] + wredL[wb+2][1] + wredL[wb+3][1];
    }

    // ---- outputs ----
    dist_out[(size_t)(b0 + rA) * AA + a] = p0 / S0;
    dist_out[(size_t)(b0 + rB) * AA + a] = p1 / S1;
    if (t == 0) {                          // rp=0: rows 0,1
        ent_out[b0 + 0] = __logf(S0) - SL0 / S0;
        ent_out[b0 + 1] = __logf(S1) - SL1 / S1;
    }
    if (t == 256) {                        // rp=1: rows 2,3
        ent_out[b0 + 2] = __logf(S0) - SL0 / S0;
        ent_out[b0 + 3] = __logf(S1) - SL1 / S1;
    }
}

extern "C" void kernel_launch(void* const* d_in, const int* in_sizes, int n_in,
                              void* d_out, int out_size, void* d_ws, size_t ws_size,
                              hipStream_t stream) {
    const int*   e          = (const int*)  d_in[0];
    const int*   q          = (const int*)  d_in[1];
    const float* H          = (const float*)d_in[2];
    const int*   r_space    = (const int*)  d_in[3];
    const float* r_mask     = (const float*)d_in[4];
    const float* entity_emb = (const float*)d_in[5];
    const float* rel_emb    = (const float*)d_in[6];
    const float* W1         = (const float*)d_in[7];
    const float* b1         = (const float*)d_in[8];
    const float* W2         = (const float*)d_in[9];
    const float* b2         = (const float*)d_in[10];

    const int B = in_sizes[0];              // 2048
    float* dist_out = (float*)d_out;                    // [B, 256]
    float* ent_out  = (float*)d_out + (size_t)B * AA;   // [B]

    policy_kernel<<<B / BB, 512, 0, stream>>>(
        e, q, H, r_space, r_mask, entity_emb, rel_emb,
        W1, b1, W2, b2, dist_out, ent_out);
}

// Round 5
// 39.200 us; speedup vs baseline: 3.3424x; 1.2682x over previous
//
#include <hip/hip_runtime.h>

// GraphSearchPolicy fused kernel, score-all-relations formulation. MI355X gfx950.
// B=2048, A=256, DE=128, DH=256, DR=128, DIN=512, ACT=256, NR=1000.
//
// Key idea: instead of gathering rel_emb[r_space[b][a]] (address-divergent,
// 64 lines per wave-instruction through L1), compute score[b][r] for ALL r
// from a pre-transposed rel_embT[k][r] (lane-consecutive r -> coalesced),
// then logits are 4-byte LDS lookups. Same L2 bytes, ~16x fewer L1 lines.
//
// Kernel 1: transpose rel_emb [1000][128] -> rel_embT [128][1000] in d_ws.
// Kernel 2: fused MLP + score GEMM + softmax + entropy. Grid 512 x 512 thr.

#define DE   128
#define DH   256
#define DR   128
#define DIN  512
#define ACT  256
#define AA   256
#define BB   4
#define NR   1000

// ---------------------------------------------------------------- transpose
__global__ __launch_bounds__(128) void transpose_kernel(
    const float* __restrict__ rel_emb, float* __restrict__ rel_embT)
{
    const int r = blockIdx.x;            // 0..999
    const int k = threadIdx.x;           // 0..127
    rel_embT[(size_t)k * NR + r] = rel_emb[(size_t)r * DR + k];
}

// ---------------------------------------------------------------- main
__global__ __launch_bounds__(512, 4) void policy_kernel(
    const int*   __restrict__ e,
    const int*   __restrict__ q,
    const float* __restrict__ H,
    const int*   __restrict__ r_space,
    const float* __restrict__ r_mask,
    const float* __restrict__ entity_emb,
    const float* __restrict__ rel_emb,
    const float* __restrict__ W1,
    const float* __restrict__ b1,
    const float* __restrict__ W2,
    const float* __restrict__ b2,
    const float* __restrict__ rel_embT,
    float* __restrict__ dist_out,
    float* __restrict__ ent_out)
{
    const int t  = threadIdx.x;          // 0..511
    const int b0 = blockIdx.x * BB;

    __shared__ __align__(16) float xvT[DIN * BB];        // [k][row]  8 KB
    __shared__ __align__(16) float part[8 * BB * ACT];   // [ks][row][col] 32 KB
    __shared__ __align__(16) float hvT[ACT * BB];        // [k][row]  4 KB
    __shared__ __align__(16) float x2T[DR * BB];         // [k][row]  2 KB
    __shared__ float scoreL[BB][NR];                     // 16 KB
    __shared__ float wredM[8][2], wredS[8][2], wredL[8][2];

    // ---- early loads: action indices + masks (latency hides under MLP) ----
    const int a  = t & 255;
    const int rp = t >> 8;               // 0..1 -> rows {2rp, 2rp+1}
    const int rA = 2 * rp, rB = rA + 1;
    const int   ridx0 = r_space[(size_t)(b0 + rA) * AA + a];
    const int   ridx1 = r_space[(size_t)(b0 + rB) * AA + a];
    const float msk0  = r_mask [(size_t)(b0 + rA) * AA + a];
    const float msk1  = r_mask [(size_t)(b0 + rB) * AA + a];

    // ---- stage X = concat(E,H,Q) transposed, conflict-free scalar rounds ----
    {
        const int srow = t & 3;          // batch row
        const int scol = t >> 2;         // 0..127
        const int sb   = b0 + srow;
        const int eb   = e[sb];
        const int qb   = q[sb];
        // round 0: k = scol           -> entity_emb
        xvT[(0 * 128 + scol) * BB + srow] = entity_emb[(size_t)eb * DE + scol];
        // rounds 1,2: k = 128..383    -> H
        xvT[(1 * 128 + scol) * BB + srow] = H[(size_t)sb * DH + scol];
        xvT[(2 * 128 + scol) * BB + srow] = H[(size_t)sb * DH + 128 + scol];
        // round 3: k = 384..511       -> rel_emb[q]
        xvT[(3 * 128 + scol) * BB + srow] = rel_emb[(size_t)qb * DR + scol];
    }
    __syncthreads();

    // ---- layer 1 partials: wave ks owns k-slice, thread owns col-quad ----
    {
        const int cq = t & 63;
        const int ks = t >> 6;           // 0..7
        float4 a0 = {0,0,0,0}, a1 = {0,0,0,0}, a2 = {0,0,0,0}, a3 = {0,0,0,0};
        const float* wbase = &W1[(size_t)(ks * 64) * ACT + cq * 4];
        const float* xbase = &xvT[(ks * 64) * BB];
        #pragma unroll 8
        for (int kk = 0; kk < 64; ++kk) {
            const float4 w = *(const float4*)(wbase + (size_t)kk * ACT);
            const float4 x = *(const float4*)(xbase + kk * BB);   // b128 bcast
            a0.x = fmaf(w.x, x.x, a0.x); a0.y = fmaf(w.y, x.x, a0.y);
            a0.z = fmaf(w.z, x.x, a0.z); a0.w = fmaf(w.w, x.x, a0.w);
            a1.x = fmaf(w.x, x.y, a1.x); a1.y = fmaf(w.y, x.y, a1.y);
            a1.z = fmaf(w.z, x.y, a1.z); a1.w = fmaf(w.w, x.y, a1.w);
            a2.x = fmaf(w.x, x.z, a2.x); a2.y = fmaf(w.y, x.z, a2.y);
            a2.z = fmaf(w.z, x.z, a2.z); a2.w = fmaf(w.w, x.z, a2.w);
            a3.x = fmaf(w.x, x.w, a3.x); a3.y = fmaf(w.y, x.w, a3.y);
            a3.z = fmaf(w.z, x.w, a3.z); a3.w = fmaf(w.w, x.w, a3.w);
        }
        float* pb = &part[(size_t)(ks * BB) * ACT + cq * 4];
        *(float4*)(pb + 0 * ACT) = a0;
        *(float4*)(pb + 1 * ACT) = a1;
        *(float4*)(pb + 2 * ACT) = a2;
        *(float4*)(pb + 3 * ACT) = a3;
    }
    __syncthreads();

    // ---- combine1 + bias + ReLU -> hvT[k][row] ----
    #pragma unroll
    for (int o = t; o < BB * ACT; o += 512) {
        const int row = o >> 8;
        const int col = o & 255;
        float s = b1[col];
        #pragma unroll
        for (int ks = 0; ks < 8; ++ks)
            s += part[(ks * BB + row) * ACT + col];
        hvT[col * BB + row] = fmaxf(s, 0.f);
    }
    __syncthreads();

    // ---- layer 2 partials ----
    {
        const int cp  = t & 63;
        const int ks2 = t >> 6;
        float2 c0 = {0,0}, c1 = {0,0}, c2 = {0,0}, c3 = {0,0};
        const float* wbase = &W2[(size_t)(ks2 * 32) * DR + cp * 2];
        const float* hbase = &hvT[(ks2 * 32) * BB];
        #pragma unroll 8
        for (int kk = 0; kk < 32; ++kk) {
            const float2 w  = *(const float2*)(wbase + (size_t)kk * DR);
            const float4 h4 = *(const float4*)(hbase + kk * BB);  // b128 bcast
            c0.x = fmaf(w.x, h4.x, c0.x); c0.y = fmaf(w.y, h4.x, c0.y);
            c1.x = fmaf(w.x, h4.y, c1.x); c1.y = fmaf(w.y, h4.y, c1.y);
            c2.x = fmaf(w.x, h4.z, c2.x); c2.y = fmaf(w.y, h4.z, c2.y);
            c3.x = fmaf(w.x, h4.w, c3.x); c3.y = fmaf(w.y, h4.w, c3.y);
        }
        float* pb = &part[(size_t)(ks2 * BB) * DR + cp * 2];
        *(float2*)(pb + 0 * DR) = c0;
        *(float2*)(pb + 1 * DR) = c1;
        *(float2*)(pb + 2 * DR) = c2;
        *(float2*)(pb + 3 * DR) = c3;
    }
    __syncthreads();

    // ---- combine2 + bias -> x2T[k][row] ----
    {
        const int row = t >> 7;          // 0..3
        const int col = t & 127;         // k of x2
        float s = b2[col];
        #pragma unroll
        for (int ks = 0; ks < 8; ++ks)
            s += part[(ks * BB + row) * DR + col];
        x2T[col * BB + row] = s;
    }
    __syncthreads();

    // ---- score GEMM: score[row][r] = sum_k x2T[k][row] * rel_embT[k][r] ----
    {
        const int r0 = t;                // always < NR
        const int r1 = t + 512;
        const bool v1 = (r1 < NR);
        const int r1c = v1 ? r1 : (NR - 1);
        float s00=0,s01=0,s02=0,s03=0, s10=0,s11=0,s12=0,s13=0;
        #pragma unroll 8
        for (int k = 0; k < DR; ++k) {
            const float w0 = rel_embT[(size_t)k * NR + r0];   // 256B/wave coalesced
            const float w1 = rel_embT[(size_t)k * NR + r1c];
            const float4 x = *(const float4*)&x2T[k * BB];    // b128 bcast
            s00 = fmaf(w0, x.x, s00); s01 = fmaf(w0, x.y, s01);
            s02 = fmaf(w0, x.z, s02); s03 = fmaf(w0, x.w, s03);
            s10 = fmaf(w1, x.x, s10); s11 = fmaf(w1, x.y, s11);
            s12 = fmaf(w1, x.z, s12); s13 = fmaf(w1, x.w, s13);
        }
        scoreL[0][r0] = s00; scoreL[1][r0] = s01;
        scoreL[2][r0] = s02; scoreL[3][r0] = s03;
        if (v1) {
            scoreL[0][r1] = s10; scoreL[1][r1] = s11;
            scoreL[2][r1] = s12; scoreL[3][r1] = s13;
        }
    }
    __syncthreads();

    // ---- logits: 4-byte LDS lookups ----
    const float lg0 = scoreL[rA][ridx0] - (1.0f - msk0) * 1e31f;
    const float lg1 = scoreL[rB][ridx1] - (1.0f - msk1) * 1e31f;

    const int wv = t >> 6;

    // ---- max ----
    float m0 = lg0, m1 = lg1;
    #pragma unroll
    for (int off = 32; off >= 1; off >>= 1) {
        m0 = fmaxf(m0, __shfl_xor(m0, off, 64));
        m1 = fmaxf(m1, __shfl_xor(m1, off, 64));
    }
    if ((t & 63) == 0) { wredM[wv][0] = m0; wredM[wv][1] = m1; }
    __syncthreads();
    {
        const int wb = rp * 4;
        m0 = fmaxf(fmaxf(wredM[wb][0], wredM[wb+1][0]), fmaxf(wredM[wb+2][0], wredM[wb+3][0]));
        m1 = fmaxf(fmaxf(wredM[wb][1], wredM[wb+1][1]), fmaxf(wredM[wb+2][1], wredM[wb+3][1]));
    }

    // ---- exp + joint sums S, SL ----
    const float z0 = lg0 - m0, z1 = lg1 - m1;
    const float p0 = __expf(z0), p1 = __expf(z1);
    float s0 = p0, s1 = p1, sl0 = p0 * z0, sl1 = p1 * z1;
    #pragma unroll
    for (int off = 32; off >= 1; off >>= 1) {
        s0  += __shfl_xor(s0,  off, 64);
        s1  += __shfl_xor(s1,  off, 64);
        sl0 += __shfl_xor(sl0, off, 64);
        sl1 += __shfl_xor(sl1, off, 64);
    }
    if ((t & 63) == 0) {
        wredS[wv][0] = s0;  wredS[wv][1] = s1;
        wredL[wv][0] = sl0; wredL[wv][1] = sl1;
    }
    __syncthreads();
    float S0, S1, SL0, SL1;
    {
        const int wb = rp * 4;
        S0  = wredS[wb][0] + wredS[wb+1][0] + wredS[wb+2][0] + wredS[wb+3][0];
        S1  = wredS[wb][1] + wredS[wb+1][1] + wredS[wb+2][1] + wredS[wb+3][1];
        SL0 = wredL[wb][0] + wredL[wb+1][0] + wredL[wb+2][0] + wredL[wb+3][0];
        SL1 = wredL[wb][1] + wredL[wb+1][1] + wredL[wb+2][1] + wredL[wb+3][1];
    }

    // ---- outputs ----
    dist_out[(size_t)(b0 + rA) * AA + a] = p0 / S0;
    dist_out[(size_t)(b0 + rB) * AA + a] = p1 / S1;
    if (t == 0) {
        ent_out[b0 + 0] = __logf(S0) - SL0 / S0;
        ent_out[b0 + 1] = __logf(S1) - SL1 / S1;
    }
    if (t == 256) {
        ent_out[b0 + 2] = __logf(S0) - SL0 / S0;
        ent_out[b0 + 3] = __logf(S1) - SL1 / S1;
    }
}

extern "C" void kernel_launch(void* const* d_in, const int* in_sizes, int n_in,
                              void* d_out, int out_size, void* d_ws, size_t ws_size,
                              hipStream_t stream) {
    const int*   e          = (const int*)  d_in[0];
    const int*   q          = (const int*)  d_in[1];
    const float* H          = (const float*)d_in[2];
    const int*   r_space    = (const int*)  d_in[3];
    const float* r_mask     = (const float*)d_in[4];
    const float* entity_emb = (const float*)d_in[5];
    const float* rel_emb    = (const float*)d_in[6];
    const float* W1         = (const float*)d_in[7];
    const float* b1         = (const float*)d_in[8];
    const float* W2         = (const float*)d_in[9];
    const float* b2         = (const float*)d_in[10];

    const int B = in_sizes[0];              // 2048
    float* dist_out = (float*)d_out;                    // [B, 256]
    float* ent_out  = (float*)d_out + (size_t)B * AA;   // [B]
    float* rel_embT = (float*)d_ws;                     // [128][1000] = 512 KB

    transpose_kernel<<<NR, 128, 0, stream>>>(rel_emb, rel_embT);
    policy_kernel<<<B / BB, 512, 0, stream>>>(
        e, q, H, r_space, r_mask, entity_emb, rel_emb,
        W1, b1, W2, b2, rel_embT, dist_out, ent_out);
}

// Round 6
// 36.252 us; speedup vs baseline: 3.6142x; 1.0813x over previous
//
#include <hip/hip_runtime.h>

// GraphSearchPolicy fused kernel, score-all-relations, BB=8. MI355X gfx950.
// B=2048, A=256, DE=128, DH=256, DR=128, DIN=512, ACT=256, NR=1000.
//
// Grid 256 blocks x 512 threads (1 block/CU, 8 waves). Per-block L2 traffic:
// W1 512KB + W2 128KB + rel_embT 512KB -> 256 x 1.15MB = 300MB (~8.5us at L2 BW),
// half of the BB=4 version. Inner loops consume shared operands as float4
// LDS broadcasts in 4-k blocks; all LDS writes lane-consecutive.

#define DE   128
#define DH   256
#define DR   128
#define DIN  512
#define ACT  256
#define AA   256
#define BB   8
#define NR   1000

// ---------------------------------------------------------------- transpose
__global__ __launch_bounds__(128) void transpose_kernel(
    const float* __restrict__ rel_emb, float* __restrict__ rel_embT)
{
    const int r = blockIdx.x;            // 0..999
    const int k = threadIdx.x;           // 0..127
    rel_embT[(size_t)k * NR + r] = rel_emb[(size_t)r * DR + k];
}

// ---------------------------------------------------------------- main
__global__ __launch_bounds__(512, 2) void policy_kernel(
    const int*   __restrict__ e,
    const int*   __restrict__ q,
    const float* __restrict__ H,
    const int*   __restrict__ r_space,
    const float* __restrict__ r_mask,
    const float* __restrict__ entity_emb,
    const float* __restrict__ rel_emb,
    const float* __restrict__ W1,
    const float* __restrict__ b1,
    const float* __restrict__ W2,
    const float* __restrict__ b2,
    const float* __restrict__ rel_embT,
    float* __restrict__ dist_out,
    float* __restrict__ ent_out)
{
    const int t  = threadIdx.x;          // 0..511
    const int b0 = blockIdx.x * BB;

    __shared__ __align__(16) float xvT[DIN * BB];     // [k][row]   16 KB
    __shared__ __align__(16) float part[8 * BB * ACT];// partials   64 KB (reused)
    __shared__ __align__(16) float hs[BB][ACT];       // [row][col]  8 KB
    __shared__ __align__(16) float x2s[BB][DR];       // [row][col]  4 KB
    __shared__ float scoreL[BB * NR];                 // 31.25 KB
    __shared__ float wredM[8][4], wredS[8][4], wredL[8][4];

    // ---- early loads: action indices + masks (latency hides under MLP) ----
    const int a   = t & 255;
    const int rp  = t >> 8;              // 0..1
    const int rp4 = rp * 4;              // this thread covers rows rp4..rp4+3
    int   ridx[4];
    float msk [4];
    #pragma unroll
    for (int j = 0; j < 4; ++j) {
        ridx[j] = r_space[(size_t)(b0 + rp4 + j) * AA + a];
        msk [j] = r_mask [(size_t)(b0 + rp4 + j) * AA + a];
    }

    // ---- stage X = concat(E,H,Q) into xvT[k][row], conflict-free rounds ----
    {
        const int srow = t & 7;
        const int scol = t >> 3;         // 0..63
        const int sb   = b0 + srow;
        const int eb   = e[sb];
        const int qb   = q[sb];
        #pragma unroll
        for (int rnd = 0; rnd < 8; ++rnd) {
            const int k = rnd * 64 + scol;
            float v;
            if (k < DE)            v = entity_emb[(size_t)eb * DE + k];
            else if (k < DE + DH)  v = H[(size_t)sb * DH + (k - DE)];
            else                   v = rel_emb[(size_t)qb * DR + (k - DE - DH)];
            xvT[k * BB + srow] = v;      // addr = rnd*512 + t : consecutive
        }
    }
    __syncthreads();

    // ---- layer 1 partials: wave ks owns 64 k, thread owns col-quad ----
    {
        const int cq = t & 63;
        const int ks = t >> 6;           // 0..7
        float4 acc[8];
        #pragma unroll
        for (int j = 0; j < 8; ++j) acc[j] = make_float4(0.f, 0.f, 0.f, 0.f);
        const float* wbase = &W1[(size_t)(ks * 64) * ACT + cq * 4];
        const float* xbase = &xvT[(ks * 64) * BB];
        #pragma unroll 4
        for (int kk = 0; kk < 64; ++kk) {
            const float4 w  = *(const float4*)(wbase + (size_t)kk * ACT); // coalesced
            const float4 xa = *(const float4*)(xbase + kk * BB);          // bcast rows 0-3
            const float4 xb = *(const float4*)(xbase + kk * BB + 4);      // bcast rows 4-7
            const float xj[8] = {xa.x, xa.y, xa.z, xa.w, xb.x, xb.y, xb.z, xb.w};
            #pragma unroll
            for (int j = 0; j < 8; ++j) {
                acc[j].x = fmaf(w.x, xj[j], acc[j].x);
                acc[j].y = fmaf(w.y, xj[j], acc[j].y);
                acc[j].z = fmaf(w.z, xj[j], acc[j].z);
                acc[j].w = fmaf(w.w, xj[j], acc[j].w);
            }
        }
        float* pb = &part[(size_t)(ks * BB) * ACT + cq * 4];
        #pragma unroll
        for (int j = 0; j < 8; ++j)
            *(float4*)(pb + (size_t)j * ACT) = acc[j];
    }
    __syncthreads();

    // ---- combine1 + bias + ReLU -> hs[row][col] ----
    #pragma unroll
    for (int i = 0; i < 4; ++i) {
        const int o   = t + i * 512;     // 0..2047
        const int row = o >> 8;
        const int col = o & 255;
        float s = b1[col];
        #pragma unroll
        for (int ks = 0; ks < 8; ++ks)
            s += part[(ks * BB + row) * ACT + col];   // lanes: consecutive col
        hs[row][col] = fmaxf(s, 0.f);                 // consecutive col write
    }
    __syncthreads();

    // ---- layer 2 partials: wave ks2 owns 32 k, thread owns col-pair ----
    {
        const int cp  = t & 63;
        const int ks2 = t >> 6;
        float2 acc[8];
        #pragma unroll
        for (int j = 0; j < 8; ++j) acc[j] = make_float2(0.f, 0.f);
        const float* wbase = &W2[(size_t)(ks2 * 32) * DR + cp * 2];
        const int k0 = ks2 * 32;
        #pragma unroll 2
        for (int k4 = 0; k4 < 32; k4 += 4) {
            float4 hr[8];
            #pragma unroll
            for (int j = 0; j < 8; ++j)
                hr[j] = *(const float4*)&hs[j][k0 + k4];      // b128 broadcast
            #define L2_STEP(COMP, KOFF)                                        \
            {                                                                  \
                const float2 w = *(const float2*)(wbase + (size_t)(k4 + KOFF) * DR); \
                _Pragma("unroll")                                              \
                for (int j = 0; j < 8; ++j) {                                  \
                    acc[j].x = fmaf(w.x, hr[j].COMP, acc[j].x);                \
                    acc[j].y = fmaf(w.y, hr[j].COMP, acc[j].y);                \
                }                                                              \
            }
            L2_STEP(x, 0) L2_STEP(y, 1) L2_STEP(z, 2) L2_STEP(w, 3)
            #undef L2_STEP
        }
        float* pb = &part[(size_t)(ks2 * BB) * DR + cp * 2];
        #pragma unroll
        for (int j = 0; j < 8; ++j)
            *(float2*)(pb + (size_t)j * DR) = acc[j];         // 512B/wave: free
    }
    __syncthreads();

    // ---- combine2 + bias -> x2s[row][col] ----
    #pragma unroll
    for (int i = 0; i < 2; ++i) {
        const int o   = t + i * 512;     // 0..1023
        const int row = o >> 7;
        const int col = o & 127;
        float s = b2[col];
        #pragma unroll
        for (int ks = 0; ks < 8; ++ks)
            s += part[(ks * BB + row) * DR + col];
        x2s[row][col] = s;
    }
    __syncthreads();

    // ---- score GEMM: scoreL[row][r] = sum_k x2s[row][k] * rel_embT[k][r] ----
    {
        const int r0  = t;               // 0..511
        const int r1  = t + 512;         // 512..1023
        const bool v1 = (r1 < NR);
        const int r1c = v1 ? r1 : (NR - 1);
        float acc0[8], acc1[8];
        #pragma unroll
        for (int j = 0; j < 8; ++j) { acc0[j] = 0.f; acc1[j] = 0.f; }
        #pragma unroll 2
        for (int k4 = 0; k4 < DR; k4 += 4) {
            float4 xr[8];
            #pragma unroll
            for (int j = 0; j < 8; ++j)
                xr[j] = *(const float4*)&x2s[j][k4];          // b128 broadcast
            #define SC_STEP(COMP, KOFF)                                        \
            {                                                                  \
                const float w0 = rel_embT[(size_t)(k4 + KOFF) * NR + r0];      \
                const float w1 = rel_embT[(size_t)(k4 + KOFF) * NR + r1c];     \
                _Pragma("unroll")                                              \
                for (int j = 0; j < 8; ++j) {                                  \
                    acc0[j] = fmaf(w0, xr[j].COMP, acc0[j]);                   \
                    acc1[j] = fmaf(w1, xr[j].COMP, acc1[j]);                   \
                }                                                              \
            }
            SC_STEP(x, 0) SC_STEP(y, 1) SC_STEP(z, 2) SC_STEP(w, 3)
            #undef SC_STEP
        }
        #pragma unroll
        for (int j = 0; j < 8; ++j) scoreL[j * NR + r0] = acc0[j];
        if (v1) {
            #pragma unroll
            for (int j = 0; j < 8; ++j) scoreL[j * NR + r1] = acc1[j];
        }
    }
    __syncthreads();

    // ---- logits: 4-byte LDS lookups for this thread's 4 rows ----
    float lg[4];
    #pragma unroll
    for (int j = 0; j < 4; ++j)
        lg[j] = scoreL[(rp4 + j) * NR + ridx[j]] - (1.0f - msk[j]) * 1e31f;

    const int wv = t >> 6;               // waves 0..3: rows 0-3; 4..7: rows 4-7

    // ---- max ----
    float m[4];
    #pragma unroll
    for (int j = 0; j < 4; ++j) m[j] = lg[j];
    #pragma unroll
    for (int off = 32; off >= 1; off >>= 1) {
        #pragma unroll
        for (int j = 0; j < 4; ++j)
            m[j] = fmaxf(m[j], __shfl_xor(m[j], off, 64));
    }
    if ((t & 63) == 0) {
        #pragma unroll
        for (int j = 0; j < 4; ++j) wredM[wv][j] = m[j];
    }
    __syncthreads();
    {
        const int wb = rp * 4;
        #pragma unroll
        for (int j = 0; j < 4; ++j)
            m[j] = fmaxf(fmaxf(wredM[wb][j], wredM[wb+1][j]),
                         fmaxf(wredM[wb+2][j], wredM[wb+3][j]));
    }

    // ---- exp + joint sums S, SL = sum p*(lg-m) ----
    float p[4], s[4], sl[4];
    #pragma unroll
    for (int j = 0; j < 4; ++j) {
        const float z = lg[j] - m[j];
        p[j]  = __expf(z);
        s[j]  = p[j];
        sl[j] = p[j] * z;
    }
    #pragma unroll
    for (int off = 32; off >= 1; off >>= 1) {
        #pragma unroll
        for (int j = 0; j < 4; ++j) {
            s[j]  += __shfl_xor(s[j],  off, 64);
            sl[j] += __shfl_xor(sl[j], off, 64);
        }
    }
    if ((t & 63) == 0) {
        #pragma unroll
        for (int j = 0; j < 4; ++j) { wredS[wv][j] = s[j]; wredL[wv][j] = sl[j]; }
    }
    __syncthreads();
    float S[4], SL[4];
    {
        const int wb = rp * 4;
        #pragma unroll
        for (int j = 0; j < 4; ++j) {
            S [j] = wredS[wb][j] + wredS[wb+1][j] + wredS[wb+2][j] + wredS[wb+3][j];
            SL[j] = wredL[wb][j] + wredL[wb+1][j] + wredL[wb+2][j] + wredL[wb+3][j];
        }
    }

    // ---- outputs ----
    #pragma unroll
    for (int j = 0; j < 4; ++j)
        dist_out[(size_t)(b0 + rp4 + j) * AA + a] = p[j] / S[j];
    if (t == 0) {
        #pragma unroll
        for (int j = 0; j < 4; ++j)
            ent_out[b0 + j] = __logf(S[j]) - SL[j] / S[j];
    }
    if (t == 256) {
        #pragma unroll
        for (int j = 0; j < 4; ++j)
            ent_out[b0 + 4 + j] = __logf(S[j]) - SL[j] / S[j];
    }
}

extern "C" void kernel_launch(void* const* d_in, const int* in_sizes, int n_in,
                              void* d_out, int out_size, void* d_ws, size_t ws_size,
                              hipStream_t stream) {
    const int*   e          = (const int*)  d_in[0];
    const int*   q          = (const int*)  d_in[1];
    const float* H          = (const float*)d_in[2];
    const int*   r_space    = (const int*)  d_in[3];
    const float* r_mask     = (const float*)d_in[4];
    const float* entity_emb = (const float*)d_in[5];
    const float* rel_emb    = (const float*)d_in[6];
    const float* W1         = (const float*)d_in[7];
    const float* b1         = (const float*)d_in[8];
    const float* W2         = (const float*)d_in[9];
    const float* b2         = (const float*)d_in[10];

    const int B = in_sizes[0];              // 2048
    float* dist_out = (float*)d_out;                    // [B, 256]
    float* ent_out  = (float*)d_out + (size_t)B * AA;   // [B]
    float* rel_embT = (float*)d_ws;                     // [128][1000] = 512 KB

    transpose_kernel<<<NR, 128, 0, stream>>>(rel_emb, rel_embT);
    policy_kernel<<<B / BB, 512, 0, stream>>>(
        e, q, H, r_space, r_mask, entity_emb, rel_emb,
        W1, b1, W2, b2, rel_embT, dist_out, ent_out);
}